// Round 1
// baseline (530.949 us; speedup 1.0000x reference)
//
#include <hip/hip_runtime.h>
#include <math.h>
#include <stdint.h>

#define SEQ 1029
#define BATCH 8
#define M_TOT (BATCH * SEQ)   /* 8232 */
#define M_PAD 8320            /* 65 * 128 */

typedef float floatx4 __attribute__((ext_vector_type(4)));
typedef __bf16 bf16x8 __attribute__((ext_vector_type(8)));

__device__ __forceinline__ unsigned short f2bf(float f) {
  union { float f; unsigned u; } v; v.f = f;
  unsigned r = v.u + 0x7fffu + ((v.u >> 16) & 1u);
  return (unsigned short)(r >> 16);
}
__device__ __forceinline__ float bf2f(unsigned short h) {
  union { unsigned u; float f; } v; v.u = ((unsigned)h) << 16;
  return v.f;
}
__device__ __forceinline__ float bf_lo(unsigned u) { union { unsigned x; float f; } v; v.x = u << 16; return v.f; }
__device__ __forceinline__ float bf_hi(unsigned u) { union { unsigned x; float f; } v; v.x = u & 0xffff0000u; return v.f; }

__device__ __forceinline__ float wave_sum(float v) {
#pragma unroll
  for (int off = 32; off > 0; off >>= 1) v += __shfl_xor(v, off, 64);
  return v;
}

/* ---------------- weight fp32 -> bf16 ---------------- */
__global__ void f2bf4_kernel(const float4* __restrict__ in, ushort4* __restrict__ out, int n4) {
  const int i = blockIdx.x * 256 + threadIdx.x;
  if (i < n4) {
    const float4 v = in[i];
    ushort4 o;
    o.x = f2bf(v.x); o.y = f2bf(v.y); o.z = f2bf(v.z); o.w = f2bf(v.w);
    out[i] = o;
  }
}

/* ---------------- LN1 for feature tokens: transpose (B,C,HW)->(rows,C) + LN ---------------- */
__global__ __launch_bounds__(256) void ln1_feat(const float* __restrict__ x,
                                                const float* __restrict__ g,
                                                const float* __restrict__ bta,
                                                unsigned short* __restrict__ xw) {
  __shared__ float tile[768 * 17];  /* [c][hw], padded stride 17 */
  const int b = blockIdx.y;
  const int hw0 = blockIdx.x * 16;
  const int t = threadIdx.x;
  const float* xb = x + (size_t)b * 768 * 1024;
  const int cl = t >> 4, hl = t & 15;
  for (int it = 0; it < 48; it++) {
    const int c = it * 16 + cl;
    tile[c * 17 + hl] = xb[(size_t)c * 1024 + hw0 + hl];
  }
  __syncthreads();
  const int wave = t >> 6, lane = t & 63;
  for (int tk = wave; tk < 16; tk += 4) {
    float vals[12], s = 0.f, ss = 0.f;
#pragma unroll
    for (int i = 0; i < 12; i++) {
      const float v = tile[(lane + 64 * i) * 17 + tk];
      vals[i] = v; s += v; ss += v * v;
    }
    s = wave_sum(s); ss = wave_sum(ss);
    const float mu = s * (1.0f / 768.0f);
    const float var = ss * (1.0f / 768.0f) - mu * mu;
    const float rs = rsqrtf(var + 1e-5f);
    const int row = b * SEQ + 5 + hw0 + tk;
    unsigned short* orow = xw + (size_t)row * 768;
#pragma unroll
    for (int i = 0; i < 12; i++) {
      const int c = lane + 64 * i;
      orow[c] = f2bf((vals[i] - mu) * rs * g[c] + bta[c]);
    }
  }
}

/* ---------------- LN1 for ctx + register tokens (40 rows, one wave each) ---------------- */
__global__ __launch_bounds__(256) void ln1_special(const float* __restrict__ ctx,
                                                   const float* __restrict__ regs,
                                                   const float* __restrict__ g,
                                                   const float* __restrict__ bta,
                                                   unsigned short* __restrict__ xw) {
  const int gw = blockIdx.x * 4 + (threadIdx.x >> 6);
  const int lane = threadIdx.x & 63;
  if (gw >= 40) return;
  const int b = gw / 5, s = gw % 5;
  const float* src = (s == 0) ? (ctx + (size_t)b * 768)
                              : (regs + ((size_t)b * 4 + (s - 1)) * 768);
  float vals[12], sm = 0.f, ss = 0.f;
#pragma unroll
  for (int i = 0; i < 12; i++) {
    const float v = src[lane + 64 * i];
    vals[i] = v; sm += v; ss += v * v;
  }
  sm = wave_sum(sm); ss = wave_sum(ss);
  const float mu = sm * (1.0f / 768.0f);
  const float var = ss * (1.0f / 768.0f) - mu * mu;
  const float rs = rsqrtf(var + 1e-5f);
  unsigned short* orow = xw + (size_t)(b * SEQ + s) * 768;
#pragma unroll
  for (int i = 0; i < 12; i++) {
    const int c = lane + 64 * i;
    orow[c] = f2bf((vals[i] - mu) * rs * g[c] + bta[c]);
  }
}

/* ---------------- zero padding rows of xw and attn ---------------- */
__global__ void zero_pads(unsigned short* __restrict__ xw, unsigned short* __restrict__ attn) {
  const int i = blockIdx.x * 256 + threadIdx.x;
  const int n = (M_PAD - M_TOT) * 768;
  if (i < n) {
    xw[(size_t)M_TOT * 768 + i] = 0;
    attn[(size_t)M_TOT * 768 + i] = 0;
  }
}

/* ---------------- bf16 MFMA GEMM: C[M,N] = A[M,K] @ W[N,K]^T + bias, epilogues ---------------- */
#define BM 128
#define BN 128
#define BK 32
#define LSTR 40  /* padded LDS row stride (elems) */

template <int EPI>
__global__ __launch_bounds__(256) void gemm_bt(const unsigned short* __restrict__ A,
                                               const unsigned short* __restrict__ W,
                                               const float* __restrict__ bias,
                                               const unsigned short* __restrict__ residb,
                                               const float* __restrict__ residf,
                                               float* __restrict__ outf,
                                               unsigned short* __restrict__ outb,
                                               int K, int N) {
  __shared__ alignas(16) unsigned short As[BM * LSTR];
  __shared__ alignas(16) unsigned short Wst[BN * LSTR];
  const int t = threadIdx.x;
  const int wave = t >> 6, lane = t & 63;
  const int quad = lane >> 4, l16 = lane & 15;
  const int wm = (wave & 1) * 64, wn = (wave >> 1) * 64;
  const int tileM = blockIdx.y * BM, tileN = blockIdx.x * BN;
  const int srow = t >> 2;
  const int scol = (t & 3) * 8;

  const floatx4 zero4 = {0.f, 0.f, 0.f, 0.f};
  floatx4 acc[4][4];
#pragma unroll
  for (int i = 0; i < 4; i++)
#pragma unroll
    for (int j = 0; j < 4; j++) acc[i][j] = zero4;

  const unsigned short* Ap = A + (size_t)tileM * K;
  const unsigned short* Wp = W + (size_t)tileN * K;

  for (int k0 = 0; k0 < K; k0 += BK) {
    const uint4 a0 = *(const uint4*)(Ap + (size_t)srow * K + k0 + scol);
    const uint4 a1 = *(const uint4*)(Ap + (size_t)(srow + 64) * K + k0 + scol);
    const uint4 w0 = *(const uint4*)(Wp + (size_t)srow * K + k0 + scol);
    const uint4 w1 = *(const uint4*)(Wp + (size_t)(srow + 64) * K + k0 + scol);
    __syncthreads();
    *(uint4*)(As + srow * LSTR + scol) = a0;
    *(uint4*)(As + (srow + 64) * LSTR + scol) = a1;
    *(uint4*)(Wst + srow * LSTR + scol) = w0;
    *(uint4*)(Wst + (srow + 64) * LSTR + scol) = w1;
    __syncthreads();
    bf16x8 af[4], wf[4];
#pragma unroll
    for (int i = 0; i < 4; i++)
      af[i] = *(const bf16x8*)(As + (wm + i * 16 + l16) * LSTR + quad * 8);
#pragma unroll
    for (int j = 0; j < 4; j++)
      wf[j] = *(const bf16x8*)(Wst + (wn + j * 16 + l16) * LSTR + quad * 8);
#pragma unroll
    for (int i = 0; i < 4; i++)
#pragma unroll
      for (int j = 0; j < 4; j++)
        acc[i][j] = __builtin_amdgcn_mfma_f32_16x16x32_bf16(af[i], wf[j], acc[i][j], 0, 0, 0);
  }

#pragma unroll
  for (int i = 0; i < 4; i++) {
    const int mbase = tileM + wm + i * 16 + quad * 4;
#pragma unroll
    for (int j = 0; j < 4; j++) {
      const int n = tileN + wn + j * 16 + l16;
      const float bv = bias[n];
#pragma unroll
      for (int r = 0; r < 4; r++) {
        const size_t idx = (size_t)(mbase + r) * N + n;
        float v = acc[i][j][r] + bv;
        if constexpr (EPI == 0) {
          outb[idx] = f2bf(v);
        } else if constexpr (EPI == 1) {
          outf[idx] = v + bf2f(residb[idx]);
        } else if constexpr (EPI == 2) {
          v = 0.5f * v * (1.0f + erff(v * 0.70710678118654752f));
          outb[idx] = f2bf(v);
        } else {
          outf[idx] = v + residf[idx];
        }
      }
    }
  }
}

/* ---------------- attention, feature rows: 6-key softmax, one wave per (b,h,s) ---------------- */
__global__ __launch_bounds__(256) void attn_feat(const unsigned short* __restrict__ qkv,
                                                 unsigned short* __restrict__ attn) {
  __shared__ float kk[5][64];
  __shared__ float vv[5][64];
  const int b = blockIdx.z, h = blockIdx.y;
  const int t = threadIdx.x;
  const size_t base = (size_t)b * SEQ;
  for (int i = t; i < 320; i += 256) {
    const int j = i >> 6, dd = i & 63;
    const size_t rb = (base + j) * 2304 + (size_t)h * 64 + dd;
    kk[j][dd] = bf2f(qkv[rb + 768]);
    vv[j][dd] = bf2f(qkv[rb + 1536]);
  }
  __syncthreads();
  const int wave = t >> 6, lane = t & 63;
  const int s = 5 + blockIdx.x * 4 + wave;
  const size_t row = (base + s) * 2304 + (size_t)h * 64;
  const float q = bf2f(qkv[row + lane]);
  const float kself = bf2f(qkv[row + 768 + lane]);
  const float vself = bf2f(qkv[row + 1536 + lane]);
  float sc[6];
#pragma unroll
  for (int j = 0; j < 5; j++) sc[j] = wave_sum(q * kk[j][lane]) * 0.125f;
  sc[5] = wave_sum(q * kself) * 0.125f;
  float mx = sc[0];
#pragma unroll
  for (int j = 1; j < 6; j++) mx = fmaxf(mx, sc[j]);
  float den = 0.f, e[6];
#pragma unroll
  for (int j = 0; j < 6; j++) { e[j] = expf(sc[j] - mx); den += e[j]; }
  const float inv = 1.0f / den;
  float o = 0.f;
#pragma unroll
  for (int j = 0; j < 5; j++) o += e[j] * vv[j][lane];
  o += e[5] * vself;
  attn[(base + s) * 768 + (size_t)h * 64 + lane] = f2bf(o * inv);
}

/* ---------------- attention, special rows 0..4: full softmax over 1029 keys ---------------- */
__global__ __launch_bounds__(256) void attn_special(const unsigned short* __restrict__ qkv,
                                                    unsigned short* __restrict__ attn) {
  __shared__ float qsh[64];
  __shared__ float sc[SEQ];
  __shared__ float red[256];
  __shared__ float outp[4][64];
  const int b = blockIdx.z, h = blockIdx.y, qi = blockIdx.x;
  const int t = threadIdx.x;
  const size_t base = (size_t)b * SEQ;
  if (t < 64) qsh[t] = bf2f(qkv[(base + qi) * 2304 + (size_t)h * 64 + t]);
  __syncthreads();
  float lmax = -1e30f;
  for (int key = t; key < SEQ; key += 256) {
    const unsigned short* kr = qkv + (base + key) * 2304 + 768 + (size_t)h * 64;
    const uint4* kr4 = (const uint4*)kr;
    float dot = 0.f;
#pragma unroll
    for (int c = 0; c < 8; c++) {
      const uint4 u = kr4[c];
      dot += qsh[c * 8 + 0] * bf_lo(u.x) + qsh[c * 8 + 1] * bf_hi(u.x)
           + qsh[c * 8 + 2] * bf_lo(u.y) + qsh[c * 8 + 3] * bf_hi(u.y)
           + qsh[c * 8 + 4] * bf_lo(u.z) + qsh[c * 8 + 5] * bf_hi(u.z)
           + qsh[c * 8 + 6] * bf_lo(u.w) + qsh[c * 8 + 7] * bf_hi(u.w);
    }
    const float v = dot * 0.125f;
    sc[key] = v;
    lmax = fmaxf(lmax, v);
  }
  red[t] = lmax;
  __syncthreads();
  for (int off = 128; off > 0; off >>= 1) {
    if (t < off) red[t] = fmaxf(red[t], red[t + off]);
    __syncthreads();
  }
  const float mx = red[0];
  __syncthreads();
  float lsum = 0.f;
  for (int key = t; key < SEQ; key += 256) {
    const float e = expf(sc[key] - mx);
    sc[key] = e;
    lsum += e;
  }
  red[t] = lsum;
  __syncthreads();
  for (int off = 128; off > 0; off >>= 1) {
    if (t < off) red[t] += red[t + off];
    __syncthreads();
  }
  const float inv = 1.0f / red[0];
  const int d = t & 63, grp = t >> 6;
  float o = 0.f;
  for (int key = grp; key < SEQ; key += 4) {
    o += sc[key] * bf2f(qkv[(base + key) * 2304 + 1536 + (size_t)h * 64 + d]);
  }
  outp[grp][d] = o;
  __syncthreads();
  if (t < 64) {
    const float sum = outp[0][d] + outp[1][d] + outp[2][d] + outp[3][d];
    attn[(base + qi) * 768 + (size_t)h * 64 + d] = f2bf(sum * inv);
  }
}

/* ---------------- LN2: wave per row over h1 (fp32) -> bf16 ---------------- */
__global__ __launch_bounds__(256) void ln2_kernel(const float* __restrict__ h1,
                                                  const float* __restrict__ g,
                                                  const float* __restrict__ bta,
                                                  unsigned short* __restrict__ out) {
  const int row = blockIdx.x * 4 + (threadIdx.x >> 6);
  const int lane = threadIdx.x & 63;
  const float* r = h1 + (size_t)row * 768;
  float vals[12], sm = 0.f, ss = 0.f;
#pragma unroll
  for (int i = 0; i < 12; i++) {
    const float v = r[lane + 64 * i];
    vals[i] = v; sm += v; ss += v * v;
  }
  sm = wave_sum(sm); ss = wave_sum(ss);
  const float mu = sm * (1.0f / 768.0f);
  const float var = ss * (1.0f / 768.0f) - mu * mu;
  const float rs = rsqrtf(var + 1e-5f);
  unsigned short* orow = out + (size_t)row * 768;
#pragma unroll
  for (int i = 0; i < 12; i++) {
    const int c = lane + 64 * i;
    orow[c] = f2bf((vals[i] - mu) * rs * g[c] + bta[c]);
  }
}

/* ---------------- final scatter: feature transpose + ctx/reg copy ---------------- */
__global__ __launch_bounds__(256) void scatter_feat(const float* __restrict__ outb,
                                                    float* __restrict__ dout) {
  __shared__ float tl[32][33];
  const int b = blockIdx.z, hw0 = blockIdx.y * 32, c0 = blockIdx.x * 32;
  const int t = threadIdx.x;
  const int i = t >> 5, j = t & 31;
#pragma unroll
  for (int r = 0; r < 4; r++) {
    const int hwi = i + r * 8;
    tl[hwi][j] = outb[(size_t)(b * SEQ + 5 + hw0 + hwi) * 768 + c0 + j];
  }
  __syncthreads();
#pragma unroll
  for (int r = 0; r < 4; r++) {
    const int ci = i + r * 8;
    dout[(size_t)b * 768 * 1024 + (size_t)(c0 + ci) * 1024 + hw0 + j] = tl[j][ci];
  }
}

__global__ void scatter_special(const float* __restrict__ outb, float* __restrict__ dout) {
  const int i = blockIdx.x * 256 + threadIdx.x;
  if (i >= 40 * 768) return;
  const int rowi = i / 768, c = i % 768;
  const int b = rowi / 5, s = rowi % 5;
  const float v = outb[(size_t)(b * SEQ + s) * 768 + c];
  if (s == 0) dout[6291456 + (size_t)b * 768 + c] = v;
  else dout[6291456 + 6144 + ((size_t)b * 4 + (s - 1)) * 768 + c] = v;
}

/* ---------------- host orchestration ---------------- */
extern "C" void kernel_launch(void* const* d_in, const int* in_sizes, int n_in,
                              void* d_out, int out_size, void* d_ws, size_t ws_size,
                              hipStream_t stream) {
  const float* x    = (const float*)d_in[0];
  const float* ctx  = (const float*)d_in[1];
  const float* regs = (const float*)d_in[2];
  const float* inw  = (const float*)d_in[3];
  const float* inb  = (const float*)d_in[4];
  const float* outw = (const float*)d_in[5];
  const float* outbi= (const float*)d_in[6];
  const float* ln1g = (const float*)d_in[7];
  const float* ln1b = (const float*)d_in[8];
  const float* ln2g = (const float*)d_in[9];
  const float* ln2b = (const float*)d_in[10];
  const float* w1   = (const float*)d_in[11];
  const float* b1   = (const float*)d_in[12];
  const float* w2   = (const float*)d_in[13];
  const float* b2   = (const float*)d_in[14];

  char* ws = (char*)d_ws;
  unsigned short* wqkv_b = (unsigned short*)(ws + 0);         /* 2304x768 bf16 */
  unsigned short* wout_b = (unsigned short*)(ws + 3538944);   /* 768x768 */
  unsigned short* w1_b   = (unsigned short*)(ws + 4718592);   /* 3072x768 */
  unsigned short* w2_b   = (unsigned short*)(ws + 9437184);   /* 768x3072 */
  unsigned short* xw_b   = (unsigned short*)(ws + 14155776);  /* M_PAD x 768 bf16 */
  unsigned short* ln2o_b = (unsigned short*)(ws + 26935296);  /* M_PAD x 768 bf16 */
  float*          h1_f   = (float*)(ws + 39714816);           /* M_PAD x 768 f32 */
  unsigned short* qkv_b  = (unsigned short*)(ws + 65273856);  /* M_PAD x 2304 bf16 */
  unsigned short* attn_b = (unsigned short*)(ws + 103612416); /* M_PAD x 768 bf16 */
  float*          out_f  = (float*)(ws + 14155776);           /* alias xw+ln2 (dead then) */
  unsigned short* ffm_b  = (unsigned short*)(ws + 65273856);  /* alias qkv+attn (dead then) */
  float* dout = (float*)d_out;

  /* weights -> bf16 */
  f2bf4_kernel<<<(442368 + 255) / 256, 256, 0, stream>>>((const float4*)inw, (ushort4*)wqkv_b, 442368);
  f2bf4_kernel<<<(147456 + 255) / 256, 256, 0, stream>>>((const float4*)outw, (ushort4*)wout_b, 147456);
  f2bf4_kernel<<<(589824 + 255) / 256, 256, 0, stream>>>((const float4*)w1, (ushort4*)w1_b, 589824);
  f2bf4_kernel<<<(589824 + 255) / 256, 256, 0, stream>>>((const float4*)w2, (ushort4*)w2_b, 589824);

  /* LN1 (+ implicit transpose of x) */
  ln1_feat<<<dim3(64, 8), 256, 0, stream>>>(x, ln1g, ln1b, xw_b);
  ln1_special<<<10, 256, 0, stream>>>(ctx, regs, ln1g, ln1b, xw_b);
  zero_pads<<<264, 256, 0, stream>>>(xw_b, attn_b);

  /* QKV */
  gemm_bt<0><<<dim3(2304 / BN, M_PAD / BM), 256, 0, stream>>>(
      xw_b, wqkv_b, inb, nullptr, nullptr, nullptr, qkv_b, 768, 2304);

  /* attention */
  attn_feat<<<dim3(256, 12, 8), 256, 0, stream>>>(qkv_b, attn_b);
  attn_special<<<dim3(5, 12, 8), 256, 0, stream>>>(qkv_b, attn_b);

  /* out-proj + residual -> h1 (fp32) */
  gemm_bt<1><<<dim3(768 / BN, M_PAD / BM), 256, 0, stream>>>(
      attn_b, wout_b, outbi, xw_b, nullptr, h1_f, nullptr, 768, 768);

  /* LN2 */
  ln2_kernel<<<M_PAD / 4, 256, 0, stream>>>(h1_f, ln2g, ln2b, ln2o_b);

  /* FF1 + exact GELU */
  gemm_bt<2><<<dim3(3072 / BN, M_PAD / BM), 256, 0, stream>>>(
      ln2o_b, w1_b, b1, nullptr, nullptr, nullptr, ffm_b, 768, 3072);

  /* FF2 + h1 residual -> out (fp32) */
  gemm_bt<3><<<dim3(768 / BN, M_PAD / BM), 256, 0, stream>>>(
      ffm_b, w2_b, b2, nullptr, h1_f, out_f, nullptr, 3072, 768);

  /* scatter outputs */
  scatter_feat<<<dim3(24, 32, 8), 256, 0, stream>>>(out_f, dout);
  scatter_special<<<120, 256, 0, stream>>>(out_f, dout);
}

// Round 2
// 522.573 us; speedup vs baseline: 1.0160x; 1.0160x over previous
//
#include <hip/hip_runtime.h>
#include <math.h>
#include <stdint.h>

#define SEQ 1029
#define BATCH 8
#define M_TOT (BATCH * SEQ)   /* 8232 */
#define M_PAD 8320            /* 65 * 128 */

typedef float floatx4 __attribute__((ext_vector_type(4)));
typedef __bf16 bf16x8 __attribute__((ext_vector_type(8)));

__device__ __forceinline__ unsigned short f2bf(float f) {
  union { float f; unsigned u; } v; v.f = f;
  unsigned r = v.u + 0x7fffu + ((v.u >> 16) & 1u);
  return (unsigned short)(r >> 16);
}
__device__ __forceinline__ float bf2f(unsigned short h) {
  union { unsigned u; float f; } v; v.u = ((unsigned)h) << 16;
  return v.f;
}
__device__ __forceinline__ float bf_lo(unsigned u) { union { unsigned x; float f; } v; v.x = u << 16; return v.f; }
__device__ __forceinline__ float bf_hi(unsigned u) { union { unsigned x; float f; } v; v.x = u & 0xffff0000u; return v.f; }

__device__ __forceinline__ float wave_sum(float v) {
#pragma unroll
  for (int off = 32; off > 0; off >>= 1) v += __shfl_xor(v, off, 64);
  return v;
}

/* async global -> LDS, 16B per lane (DMA writes lds base + lane*16) */
__device__ __forceinline__ void gload16(const unsigned short* g, unsigned short* l) {
  __builtin_amdgcn_global_load_lds(
      (const __attribute__((address_space(1))) unsigned int*)g,
      (__attribute__((address_space(3))) unsigned int*)l, 16, 0, 0);
}

/* ---------------- weight fp32 -> bf16 ---------------- */
__global__ void f2bf4_kernel(const float4* __restrict__ in, ushort4* __restrict__ out, int n4) {
  const int i = blockIdx.x * 256 + threadIdx.x;
  if (i < n4) {
    const float4 v = in[i];
    ushort4 o;
    o.x = f2bf(v.x); o.y = f2bf(v.y); o.z = f2bf(v.z); o.w = f2bf(v.w);
    out[i] = o;
  }
}

/* ---------------- LN1 for feature tokens: transpose (B,C,HW)->(rows,C) + LN ---------------- */
__global__ __launch_bounds__(256) void ln1_feat(const float* __restrict__ x,
                                                const float* __restrict__ g,
                                                const float* __restrict__ bta,
                                                unsigned short* __restrict__ xw) {
  __shared__ float tile[768 * 17];  /* [c][hw], padded stride 17 */
  const int b = blockIdx.y;
  const int hw0 = blockIdx.x * 16;
  const int t = threadIdx.x;
  const float* xb = x + (size_t)b * 768 * 1024;
  const int cl = t >> 4, hl = t & 15;
  for (int it = 0; it < 48; it++) {
    const int c = it * 16 + cl;
    tile[c * 17 + hl] = xb[(size_t)c * 1024 + hw0 + hl];
  }
  __syncthreads();
  const int wave = t >> 6, lane = t & 63;
  for (int tk = wave; tk < 16; tk += 4) {
    float vals[12], s = 0.f, ss = 0.f;
#pragma unroll
    for (int i = 0; i < 12; i++) {
      const float v = tile[(lane + 64 * i) * 17 + tk];
      vals[i] = v; s += v; ss += v * v;
    }
    s = wave_sum(s); ss = wave_sum(ss);
    const float mu = s * (1.0f / 768.0f);
    const float var = ss * (1.0f / 768.0f) - mu * mu;
    const float rs = rsqrtf(var + 1e-5f);
    const int row = b * SEQ + 5 + hw0 + tk;
    unsigned short* orow = xw + (size_t)row * 768;
#pragma unroll
    for (int i = 0; i < 12; i++) {
      const int c = lane + 64 * i;
      orow[c] = f2bf((vals[i] - mu) * rs * g[c] + bta[c]);
    }
  }
}

/* ---------------- LN1 for ctx + register tokens (40 rows, one wave each) ---------------- */
__global__ __launch_bounds__(256) void ln1_special(const float* __restrict__ ctx,
                                                   const float* __restrict__ regs,
                                                   const float* __restrict__ g,
                                                   const float* __restrict__ bta,
                                                   unsigned short* __restrict__ xw) {
  const int gw = blockIdx.x * 4 + (threadIdx.x >> 6);
  const int lane = threadIdx.x & 63;
  if (gw >= 40) return;
  const int b = gw / 5, s = gw % 5;
  const float* src = (s == 0) ? (ctx + (size_t)b * 768)
                              : (regs + ((size_t)b * 4 + (s - 1)) * 768);
  float vals[12], sm = 0.f, ss = 0.f;
#pragma unroll
  for (int i = 0; i < 12; i++) {
    const float v = src[lane + 64 * i];
    vals[i] = v; sm += v; ss += v * v;
  }
  sm = wave_sum(sm); ss = wave_sum(ss);
  const float mu = sm * (1.0f / 768.0f);
  const float var = ss * (1.0f / 768.0f) - mu * mu;
  const float rs = rsqrtf(var + 1e-5f);
  unsigned short* orow = xw + (size_t)(b * SEQ + s) * 768;
#pragma unroll
  for (int i = 0; i < 12; i++) {
    const int c = lane + 64 * i;
    orow[c] = f2bf((vals[i] - mu) * rs * g[c] + bta[c]);
  }
}

/* ---------------- zero padding rows of xw and attn ---------------- */
__global__ void zero_pads(unsigned short* __restrict__ xw, unsigned short* __restrict__ attn) {
  const int i = blockIdx.x * 256 + threadIdx.x;
  const int n = (M_PAD - M_TOT) * 768;
  if (i < n) {
    xw[(size_t)M_TOT * 768 + i] = 0;
    attn[(size_t)M_TOT * 768 + i] = 0;
  }
}

/* ---------------- bf16 MFMA GEMM: C[M,N] = A[M,K] @ W[N,K]^T + bias, epilogues
   m97 structure: global_load_lds width=16 staging, unpadded LDS, XOR chunk swizzle
   (LDS slot s of row r holds k-chunk s ^ ((r>>1)&3)) so per-quad fragment reads
   alias only 2-way (free) instead of 8-way. ---------------- */
#define BM 128
#define BN 128
#define BK 32

template <int EPI>
__global__ __launch_bounds__(256) void gemm_bt(const unsigned short* __restrict__ A,
                                               const unsigned short* __restrict__ W,
                                               const float* __restrict__ bias,
                                               const unsigned short* __restrict__ residb,
                                               const float* __restrict__ residf,
                                               float* __restrict__ outf,
                                               unsigned short* __restrict__ outb,
                                               int K, int N) {
  __shared__ alignas(16) unsigned short As[BM * BK];   /* 8 KiB, unpadded */
  __shared__ alignas(16) unsigned short Ws[BN * BK];   /* 8 KiB, unpadded */
  const int t = threadIdx.x;
  const int wave = t >> 6, lane = t & 63;
  const int quad = lane >> 4, l16 = lane & 15;
  const int wm = (wave & 1) * 64, wn = (wave >> 1) * 64;
  const int tileM = blockIdx.y * BM, tileN = blockIdx.x * BN;

  /* staging geometry: each wave issues 2x A + 2x B 1KiB DMAs per K-step.
     lane l covers (row_local = l>>2, slot = l&3); the global chunk fetched
     into slot is swizzled: kc = slot ^ ((row_local>>1)&3). */
  const int rl = lane >> 2;
  const int kc8 = ((lane & 3) ^ ((rl >> 1) & 3)) * 8; /* element offset */
  const unsigned short* Ag = A + (size_t)(tileM + wave * 16 + rl) * K;
  const unsigned short* Wg = W + (size_t)(tileN + wave * 16 + rl) * K;
  unsigned short* Al = As + wave * 512 + lane * 8;
  unsigned short* Wl = Ws + wave * 512 + lane * 8;

  /* fragment-read swizzle: row bits 1..2 come from l16 */
  const int koff = ((quad ^ ((l16 >> 1) & 3)) * 8);

  const floatx4 zero4 = {0.f, 0.f, 0.f, 0.f};
  floatx4 acc[4][4];
#pragma unroll
  for (int i = 0; i < 4; i++)
#pragma unroll
    for (int j = 0; j < 4; j++) acc[i][j] = zero4;

  for (int k0 = 0; k0 < K; k0 += BK) {
    gload16(Ag + k0 + kc8, Al);
    gload16(Ag + (size_t)64 * K + k0 + kc8, Al + 2048);
    gload16(Wg + k0 + kc8, Wl);
    gload16(Wg + (size_t)64 * K + k0 + kc8, Wl + 2048);
    __syncthreads();  /* drains vmcnt: DMA complete, tile visible */
    bf16x8 af[4], wf[4];
#pragma unroll
    for (int i = 0; i < 4; i++)
      af[i] = *(const bf16x8*)(As + (wm + i * 16 + l16) * BK + koff);
#pragma unroll
    for (int j = 0; j < 4; j++)
      wf[j] = *(const bf16x8*)(Ws + (wn + j * 16 + l16) * BK + koff);
#pragma unroll
    for (int i = 0; i < 4; i++)
#pragma unroll
      for (int j = 0; j < 4; j++)
        acc[i][j] = __builtin_amdgcn_mfma_f32_16x16x32_bf16(af[i], wf[j], acc[i][j], 0, 0, 0);
    __syncthreads();  /* reads done before next DMA overwrites */
  }

#pragma unroll
  for (int i = 0; i < 4; i++) {
    const int mbase = tileM + wm + i * 16 + quad * 4;
#pragma unroll
    for (int j = 0; j < 4; j++) {
      const int n = tileN + wn + j * 16 + l16;
      const float bv = bias[n];
#pragma unroll
      for (int r = 0; r < 4; r++) {
        const size_t idx = (size_t)(mbase + r) * N + n;
        float v = acc[i][j][r] + bv;
        if constexpr (EPI == 0) {
          outb[idx] = f2bf(v);
        } else if constexpr (EPI == 1) {
          outf[idx] = v + bf2f(residb[idx]);
        } else if constexpr (EPI == 2) {
          v = 0.5f * v * (1.0f + erff(v * 0.70710678118654752f));
          outb[idx] = f2bf(v);
        } else {
          outf[idx] = v + residf[idx];
        }
      }
    }
  }
}

/* ---------------- attention, feature rows: 6-key softmax, one wave per (b,h,s) ---------------- */
__global__ __launch_bounds__(256) void attn_feat(const unsigned short* __restrict__ qkv,
                                                 unsigned short* __restrict__ attn) {
  __shared__ float kk[5][64];
  __shared__ float vv[5][64];
  const int b = blockIdx.z, h = blockIdx.y;
  const int t = threadIdx.x;
  const size_t base = (size_t)b * SEQ;
  for (int i = t; i < 320; i += 256) {
    const int j = i >> 6, dd = i & 63;
    const size_t rb = (base + j) * 2304 + (size_t)h * 64 + dd;
    kk[j][dd] = bf2f(qkv[rb + 768]);
    vv[j][dd] = bf2f(qkv[rb + 1536]);
  }
  __syncthreads();
  const int wave = t >> 6, lane = t & 63;
  const int s = 5 + blockIdx.x * 4 + wave;
  const size_t row = (base + s) * 2304 + (size_t)h * 64;
  const float q = bf2f(qkv[row + lane]);
  const float kself = bf2f(qkv[row + 768 + lane]);
  const float vself = bf2f(qkv[row + 1536 + lane]);
  float sc[6];
#pragma unroll
  for (int j = 0; j < 5; j++) sc[j] = wave_sum(q * kk[j][lane]) * 0.125f;
  sc[5] = wave_sum(q * kself) * 0.125f;
  float mx = sc[0];
#pragma unroll
  for (int j = 1; j < 6; j++) mx = fmaxf(mx, sc[j]);
  float den = 0.f, e[6];
#pragma unroll
  for (int j = 0; j < 6; j++) { e[j] = expf(sc[j] - mx); den += e[j]; }
  const float inv = 1.0f / den;
  float o = 0.f;
#pragma unroll
  for (int j = 0; j < 5; j++) o += e[j] * vv[j][lane];
  o += e[5] * vself;
  attn[(base + s) * 768 + (size_t)h * 64 + lane] = f2bf(o * inv);
}

/* ---------------- attention, special rows 0..4: full softmax over 1029 keys ---------------- */
__global__ __launch_bounds__(256) void attn_special(const unsigned short* __restrict__ qkv,
                                                    unsigned short* __restrict__ attn) {
  __shared__ float qsh[64];
  __shared__ float sc[SEQ];
  __shared__ float red[256];
  __shared__ float outp[4][64];
  const int b = blockIdx.z, h = blockIdx.y, qi = blockIdx.x;
  const int t = threadIdx.x;
  const size_t base = (size_t)b * SEQ;
  if (t < 64) qsh[t] = bf2f(qkv[(base + qi) * 2304 + (size_t)h * 64 + t]);
  __syncthreads();
  float lmax = -1e30f;
  for (int key = t; key < SEQ; key += 256) {
    const unsigned short* kr = qkv + (base + key) * 2304 + 768 + (size_t)h * 64;
    const uint4* kr4 = (const uint4*)kr;
    float dot = 0.f;
#pragma unroll
    for (int c = 0; c < 8; c++) {
      const uint4 u = kr4[c];
      dot += qsh[c * 8 + 0] * bf_lo(u.x) + qsh[c * 8 + 1] * bf_hi(u.x)
           + qsh[c * 8 + 2] * bf_lo(u.y) + qsh[c * 8 + 3] * bf_hi(u.y)
           + qsh[c * 8 + 4] * bf_lo(u.z) + qsh[c * 8 + 5] * bf_hi(u.z)
           + qsh[c * 8 + 6] * bf_lo(u.w) + qsh[c * 8 + 7] * bf_hi(u.w);
    }
    const float v = dot * 0.125f;
    sc[key] = v;
    lmax = fmaxf(lmax, v);
  }
  red[t] = lmax;
  __syncthreads();
  for (int off = 128; off > 0; off >>= 1) {
    if (t < off) red[t] = fmaxf(red[t], red[t + off]);
    __syncthreads();
  }
  const float mx = red[0];
  __syncthreads();
  float lsum = 0.f;
  for (int key = t; key < SEQ; key += 256) {
    const float e = expf(sc[key] - mx);
    sc[key] = e;
    lsum += e;
  }
  red[t] = lsum;
  __syncthreads();
  for (int off = 128; off > 0; off >>= 1) {
    if (t < off) red[t] += red[t + off];
    __syncthreads();
  }
  const float inv = 1.0f / red[0];
  const int d = t & 63, grp = t >> 6;
  float o = 0.f;
  for (int key = grp; key < SEQ; key += 4) {
    o += sc[key] * bf2f(qkv[(base + key) * 2304 + 1536 + (size_t)h * 64 + d]);
  }
  outp[grp][d] = o;
  __syncthreads();
  if (t < 64) {
    const float sum = outp[0][d] + outp[1][d] + outp[2][d] + outp[3][d];
    attn[(base + qi) * 768 + (size_t)h * 64 + d] = f2bf(sum * inv);
  }
}

/* ---------------- LN2: wave per row over h1 (fp32) -> bf16 ---------------- */
__global__ __launch_bounds__(256) void ln2_kernel(const float* __restrict__ h1,
                                                  const float* __restrict__ g,
                                                  const float* __restrict__ bta,
                                                  unsigned short* __restrict__ out) {
  const int row = blockIdx.x * 4 + (threadIdx.x >> 6);
  const int lane = threadIdx.x & 63;
  const float* r = h1 + (size_t)row * 768;
  float vals[12], sm = 0.f, ss = 0.f;
#pragma unroll
  for (int i = 0; i < 12; i++) {
    const float v = r[lane + 64 * i];
    vals[i] = v; sm += v; ss += v * v;
  }
  sm = wave_sum(sm); ss = wave_sum(ss);
  const float mu = sm * (1.0f / 768.0f);
  const float var = ss * (1.0f / 768.0f) - mu * mu;
  const float rs = rsqrtf(var + 1e-5f);
  unsigned short* orow = out + (size_t)row * 768;
#pragma unroll
  for (int i = 0; i < 12; i++) {
    const int c = lane + 64 * i;
    orow[c] = f2bf((vals[i] - mu) * rs * g[c] + bta[c]);
  }
}

/* ---------------- final scatter: feature transpose + ctx/reg copy ---------------- */
__global__ __launch_bounds__(256) void scatter_feat(const float* __restrict__ outb,
                                                    float* __restrict__ dout) {
  __shared__ float tl[32][33];
  const int b = blockIdx.z, hw0 = blockIdx.y * 32, c0 = blockIdx.x * 32;
  const int t = threadIdx.x;
  const int i = t >> 5, j = t & 31;
#pragma unroll
  for (int r = 0; r < 4; r++) {
    const int hwi = i + r * 8;
    tl[hwi][j] = outb[(size_t)(b * SEQ + 5 + hw0 + hwi) * 768 + c0 + j];
  }
  __syncthreads();
#pragma unroll
  for (int r = 0; r < 4; r++) {
    const int ci = i + r * 8;
    dout[(size_t)b * 768 * 1024 + (size_t)(c0 + ci) * 1024 + hw0 + j] = tl[j][ci];
  }
}

__global__ void scatter_special(const float* __restrict__ outb, float* __restrict__ dout) {
  const int i = blockIdx.x * 256 + threadIdx.x;
  if (i >= 40 * 768) return;
  const int rowi = i / 768, c = i % 768;
  const int b = rowi / 5, s = rowi % 5;
  const float v = outb[(size_t)(b * SEQ + s) * 768 + c];
  if (s == 0) dout[6291456 + (size_t)b * 768 + c] = v;
  else dout[6291456 + 6144 + ((size_t)b * 4 + (s - 1)) * 768 + c] = v;
}

/* ---------------- host orchestration ---------------- */
extern "C" void kernel_launch(void* const* d_in, const int* in_sizes, int n_in,
                              void* d_out, int out_size, void* d_ws, size_t ws_size,
                              hipStream_t stream) {
  const float* x    = (const float*)d_in[0];
  const float* ctx  = (const float*)d_in[1];
  const float* regs = (const float*)d_in[2];
  const float* inw  = (const float*)d_in[3];
  const float* inb  = (const float*)d_in[4];
  const float* outw = (const float*)d_in[5];
  const float* outbi= (const float*)d_in[6];
  const float* ln1g = (const float*)d_in[7];
  const float* ln1b = (const float*)d_in[8];
  const float* ln2g = (const float*)d_in[9];
  const float* ln2b = (const float*)d_in[10];
  const float* w1   = (const float*)d_in[11];
  const float* b1   = (const float*)d_in[12];
  const float* w2   = (const float*)d_in[13];
  const float* b2   = (const float*)d_in[14];

  char* ws = (char*)d_ws;
  unsigned short* wqkv_b = (unsigned short*)(ws + 0);         /* 2304x768 bf16 */
  unsigned short* wout_b = (unsigned short*)(ws + 3538944);   /* 768x768 */
  unsigned short* w1_b   = (unsigned short*)(ws + 4718592);   /* 3072x768 */
  unsigned short* w2_b   = (unsigned short*)(ws + 9437184);   /* 768x3072 */
  unsigned short* xw_b   = (unsigned short*)(ws + 14155776);  /* M_PAD x 768 bf16 */
  unsigned short* ln2o_b = (unsigned short*)(ws + 26935296);  /* M_PAD x 768 bf16 */
  float*          h1_f   = (float*)(ws + 39714816);           /* M_PAD x 768 f32 */
  unsigned short* qkv_b  = (unsigned short*)(ws + 65273856);  /* M_PAD x 2304 bf16 */
  unsigned short* attn_b = (unsigned short*)(ws + 103612416); /* M_PAD x 768 bf16 */
  float*          out_f  = (float*)(ws + 14155776);           /* alias xw+ln2 (dead then) */
  unsigned short* ffm_b  = (unsigned short*)(ws + 65273856);  /* alias qkv+attn (dead then) */
  float* dout = (float*)d_out;

  /* weights -> bf16 */
  f2bf4_kernel<<<(442368 + 255) / 256, 256, 0, stream>>>((const float4*)inw, (ushort4*)wqkv_b, 442368);
  f2bf4_kernel<<<(147456 + 255) / 256, 256, 0, stream>>>((const float4*)outw, (ushort4*)wout_b, 147456);
  f2bf4_kernel<<<(589824 + 255) / 256, 256, 0, stream>>>((const float4*)w1, (ushort4*)w1_b, 589824);
  f2bf4_kernel<<<(589824 + 255) / 256, 256, 0, stream>>>((const float4*)w2, (ushort4*)w2_b, 589824);

  /* LN1 (+ implicit transpose of x) */
  ln1_feat<<<dim3(64, 8), 256, 0, stream>>>(x, ln1g, ln1b, xw_b);
  ln1_special<<<10, 256, 0, stream>>>(ctx, regs, ln1g, ln1b, xw_b);
  zero_pads<<<264, 256, 0, stream>>>(xw_b, attn_b);

  /* QKV */
  gemm_bt<0><<<dim3(2304 / BN, M_PAD / BM), 256, 0, stream>>>(
      xw_b, wqkv_b, inb, nullptr, nullptr, nullptr, qkv_b, 768, 2304);

  /* attention */
  attn_feat<<<dim3(256, 12, 8), 256, 0, stream>>>(qkv_b, attn_b);
  attn_special<<<dim3(5, 12, 8), 256, 0, stream>>>(qkv_b, attn_b);

  /* out-proj + residual -> h1 (fp32) */
  gemm_bt<1><<<dim3(768 / BN, M_PAD / BM), 256, 0, stream>>>(
      attn_b, wout_b, outbi, xw_b, nullptr, h1_f, nullptr, 768, 768);

  /* LN2 */
  ln2_kernel<<<M_PAD / 4, 256, 0, stream>>>(h1_f, ln2g, ln2b, ln2o_b);

  /* FF1 + exact GELU */
  gemm_bt<2><<<dim3(3072 / BN, M_PAD / BM), 256, 0, stream>>>(
      ln2o_b, w1_b, b1, nullptr, nullptr, nullptr, ffm_b, 768, 3072);

  /* FF2 + h1 residual -> out (fp32) */
  gemm_bt<3><<<dim3(768 / BN, M_PAD / BM), 256, 0, stream>>>(
      ffm_b, w2_b, b2, nullptr, h1_f, out_f, nullptr, 3072, 768);

  /* scatter outputs */
  scatter_feat<<<dim3(24, 32, 8), 256, 0, stream>>>(out_f, dout);
  scatter_special<<<120, 256, 0, stream>>>(out_f, dout);
}

// Round 3
// 493.634 us; speedup vs baseline: 1.0756x; 1.0586x over previous
//
#include <hip/hip_runtime.h>
#include <math.h>
#include <stdint.h>

#define SEQ 1029
#define BATCH 8
#define M_TOT (BATCH * SEQ)   /* 8232 */
#define M_PAD 8320            /* 65 * 128 */

typedef float floatx4 __attribute__((ext_vector_type(4)));
typedef __bf16 bf16x8 __attribute__((ext_vector_type(8)));

__device__ __forceinline__ unsigned short f2bf(float f) {
  union { float f; unsigned u; } v; v.f = f;
  unsigned r = v.u + 0x7fffu + ((v.u >> 16) & 1u);
  return (unsigned short)(r >> 16);
}
__device__ __forceinline__ float bf2f(unsigned short h) {
  union { unsigned u; float f; } v; v.u = ((unsigned)h) << 16;
  return v.f;
}
__device__ __forceinline__ float bf_lo(unsigned u) { union { unsigned x; float f; } v; v.x = u << 16; return v.f; }
__device__ __forceinline__ float bf_hi(unsigned u) { union { unsigned x; float f; } v; v.x = u & 0xffff0000u; return v.f; }

__device__ __forceinline__ float wave_sum(float v) {
#pragma unroll
  for (int off = 32; off > 0; off >>= 1) v += __shfl_xor(v, off, 64);
  return v;
}

/* async global -> LDS, 16B per lane (DMA writes lds base + lane*16) */
__device__ __forceinline__ void gload16(const unsigned short* g, unsigned short* l) {
  __builtin_amdgcn_global_load_lds(
      (const __attribute__((address_space(1))) unsigned int*)g,
      (__attribute__((address_space(3))) unsigned int*)l, 16, 0, 0);
}

/* ---------------- fused prep: all weights fp32 -> bf16, plus zero-fill pad rows ---------------- */
#define NQ_QKV 442368
#define NQ_OUT 147456
#define NQ_W1  589824
#define NQ_W2  589824
#define NQ_PAD 8448   /* (M_PAD-M_TOT)*768/8 ushort4 quads */
__global__ void convert_all(const float4* __restrict__ inw, const float4* __restrict__ outw,
                            const float4* __restrict__ w1, const float4* __restrict__ w2,
                            ushort4* __restrict__ wqkv, ushort4* __restrict__ wout,
                            ushort4* __restrict__ w1b, ushort4* __restrict__ w2b,
                            ushort4* __restrict__ xw_pad, ushort4* __restrict__ attn_pad) {
  const int i = blockIdx.x * 256 + threadIdx.x;
  const float4* src; ushort4* dst; int off;
  if (i < NQ_QKV) { src = inw; dst = wqkv; off = i; }
  else if (i < NQ_QKV + NQ_OUT) { src = outw; dst = wout; off = i - NQ_QKV; }
  else if (i < NQ_QKV + NQ_OUT + NQ_W1) { src = w1; dst = w1b; off = i - NQ_QKV - NQ_OUT; }
  else if (i < NQ_QKV + NQ_OUT + NQ_W1 + NQ_W2) { src = w2; dst = w2b; off = i - NQ_QKV - NQ_OUT - NQ_W1; }
  else {
    const int j = i - (NQ_QKV + NQ_OUT + NQ_W1 + NQ_W2);
    const ushort4 z = {0, 0, 0, 0};
    if (j < NQ_PAD) { xw_pad[j] = z; attn_pad[j] = z; }
    return;
  }
  const float4 v = src[off];
  ushort4 o;
  o.x = f2bf(v.x); o.y = f2bf(v.y); o.z = f2bf(v.z); o.w = f2bf(v.w);
  dst[off] = o;
}
#define NQ_ALL (NQ_QKV + NQ_OUT + NQ_W1 + NQ_W2 + NQ_PAD)

/* ---------------- LN1 for feature tokens: transpose (B,C,HW)->(rows,C) + LN ---------------- */
__global__ __launch_bounds__(256) void ln1_feat(const float* __restrict__ x,
                                                const float* __restrict__ g,
                                                const float* __restrict__ bta,
                                                unsigned short* __restrict__ xw) {
  __shared__ float tile[768 * 17];  /* [c][hw], padded stride 17 */
  const int b = blockIdx.y;
  const int hw0 = blockIdx.x * 16;
  const int t = threadIdx.x;
  const float* xb = x + (size_t)b * 768 * 1024;
  const int cl = t >> 4, hl = t & 15;
  for (int it = 0; it < 48; it++) {
    const int c = it * 16 + cl;
    tile[c * 17 + hl] = xb[(size_t)c * 1024 + hw0 + hl];
  }
  __syncthreads();
  const int wave = t >> 6, lane = t & 63;
  for (int tk = wave; tk < 16; tk += 4) {
    float vals[12], s = 0.f, ss = 0.f;
#pragma unroll
    for (int i = 0; i < 12; i++) {
      const float v = tile[(lane + 64 * i) * 17 + tk];
      vals[i] = v; s += v; ss += v * v;
    }
    s = wave_sum(s); ss = wave_sum(ss);
    const float mu = s * (1.0f / 768.0f);
    const float var = ss * (1.0f / 768.0f) - mu * mu;
    const float rs = rsqrtf(var + 1e-5f);
    const int row = b * SEQ + 5 + hw0 + tk;
    unsigned short* orow = xw + (size_t)row * 768;
#pragma unroll
    for (int i = 0; i < 12; i++) {
      const int c = lane + 64 * i;
      orow[c] = f2bf((vals[i] - mu) * rs * g[c] + bta[c]);
    }
  }
}

/* ---------------- LN1 for ctx + register tokens (40 rows, one wave each) ---------------- */
__global__ __launch_bounds__(256) void ln1_special(const float* __restrict__ ctx,
                                                   const float* __restrict__ regs,
                                                   const float* __restrict__ g,
                                                   const float* __restrict__ bta,
                                                   unsigned short* __restrict__ xw) {
  const int gw = blockIdx.x * 4 + (threadIdx.x >> 6);
  const int lane = threadIdx.x & 63;
  if (gw >= 40) return;
  const int b = gw / 5, s = gw % 5;
  const float* src = (s == 0) ? (ctx + (size_t)b * 768)
                              : (regs + ((size_t)b * 4 + (s - 1)) * 768);
  float vals[12], sm = 0.f, ss = 0.f;
#pragma unroll
  for (int i = 0; i < 12; i++) {
    const float v = src[lane + 64 * i];
    vals[i] = v; sm += v; ss += v * v;
  }
  sm = wave_sum(sm); ss = wave_sum(ss);
  const float mu = sm * (1.0f / 768.0f);
  const float var = ss * (1.0f / 768.0f) - mu * mu;
  const float rs = rsqrtf(var + 1e-5f);
  unsigned short* orow = xw + (size_t)(b * SEQ + s) * 768;
#pragma unroll
  for (int i = 0; i < 12; i++) {
    const int c = lane + 64 * i;
    orow[c] = f2bf((vals[i] - mu) * rs * g[c] + bta[c]);
  }
}

/* ---------------- bf16 MFMA GEMM: C[M,N] = A[M,K] @ W[N,K]^T + bias, epilogues
   Double-buffered LDS (2x16KiB), ONE barrier per K-step: DMA for step k+1 is
   issued right after the barrier, so its latency overlaps step-k ds_read+MFMA
   instead of being drained immediately (the round-2 structural stall).
   XOR chunk swizzle keeps fragment reads 2-way (free). K,N compile-time. ---------------- */
#define BM 128
#define BN 128
#define BK 32

template <int EPI, int K, int N>
__global__ __launch_bounds__(256, 4) void gemm_bt(const unsigned short* __restrict__ A,
                                                  const unsigned short* __restrict__ W,
                                                  const float* __restrict__ bias,
                                                  const unsigned short* __restrict__ residb,
                                                  const float* __restrict__ residf,
                                                  float* __restrict__ outf,
                                                  unsigned short* __restrict__ outb) {
  __shared__ alignas(16) unsigned short As[2][BM * BK];   /* 2 x 8 KiB */
  __shared__ alignas(16) unsigned short Ws[2][BN * BK];
  const int t = threadIdx.x;
  const int wave = t >> 6, lane = t & 63;
  const int quad = lane >> 4, l16 = lane & 15;
  const int wm = (wave & 1) * 64, wn = (wave >> 1) * 64;
  const int tileM = blockIdx.y * BM, tileN = blockIdx.x * BN;

  /* staging geometry: lane l covers (row_local = l>>2, slot = l&3); global chunk
     fetched into slot is swizzled: kc = slot ^ ((row_local>>1)&3). */
  const int rl = lane >> 2;
  const int kc8 = ((lane & 3) ^ ((rl >> 1) & 3)) * 8;
  const unsigned short* Ag = A + (size_t)(tileM + wave * 16 + rl) * K;
  const unsigned short* Wg = W + (size_t)(tileN + wave * 16 + rl) * K;
  const int ldst = wave * 512 + lane * 8;

  /* fragment-read swizzle */
  const int koff = ((quad ^ ((l16 >> 1) & 3)) * 8);

  const floatx4 zero4 = {0.f, 0.f, 0.f, 0.f};
  floatx4 acc[4][4];
#pragma unroll
  for (int i = 0; i < 4; i++)
#pragma unroll
    for (int j = 0; j < 4; j++) acc[i][j] = zero4;

  auto dma = [&](int k0, int buf) {
    gload16(Ag + k0 + kc8, &As[buf][0] + ldst);
    gload16(Ag + (size_t)64 * K + k0 + kc8, &As[buf][0] + ldst + 2048);
    gload16(Wg + k0 + kc8, &Ws[buf][0] + ldst);
    gload16(Wg + (size_t)64 * K + k0 + kc8, &Ws[buf][0] + ldst + 2048);
  };
  auto compute = [&](int buf) {
    bf16x8 af[4], wf[4];
#pragma unroll
    for (int i = 0; i < 4; i++)
      af[i] = *(const bf16x8*)(&As[buf][0] + (wm + i * 16 + l16) * BK + koff);
#pragma unroll
    for (int j = 0; j < 4; j++)
      wf[j] = *(const bf16x8*)(&Ws[buf][0] + (wn + j * 16 + l16) * BK + koff);
#pragma unroll
    for (int i = 0; i < 4; i++)
#pragma unroll
      for (int j = 0; j < 4; j++)
        acc[i][j] = __builtin_amdgcn_mfma_f32_16x16x32_bf16(af[i], wf[j], acc[i][j], 0, 0, 0);
  };

  dma(0, 0);
#pragma unroll 1
  for (int k0 = 0; k0 < K; k0 += 2 * BK) {
    __syncthreads();              /* drains buf0 DMA; overlapped with prior compute */
    if (k0 + BK < K) dma(k0 + BK, 1);
    compute(0);
    __syncthreads();              /* drains buf1 DMA */
    if (k0 + 2 * BK < K) dma(k0 + 2 * BK, 0);
    compute(1);
  }

#pragma unroll
  for (int i = 0; i < 4; i++) {
    const int mbase = tileM + wm + i * 16 + quad * 4;
#pragma unroll
    for (int j = 0; j < 4; j++) {
      const int n = tileN + wn + j * 16 + l16;
      const float bv = bias[n];
#pragma unroll
      for (int r = 0; r < 4; r++) {
        const size_t idx = (size_t)(mbase + r) * N + n;
        float v = acc[i][j][r] + bv;
        if constexpr (EPI == 0) {
          outb[idx] = f2bf(v);
        } else if constexpr (EPI == 1) {
          outf[idx] = v + bf2f(residb[idx]);
        } else if constexpr (EPI == 2) {
          v = 0.5f * v * (1.0f + erff(v * 0.70710678118654752f));
          outb[idx] = f2bf(v);
        } else {
          outf[idx] = v + residf[idx];
        }
      }
    }
  }
}

/* ---------------- attention, feature rows: 6-key softmax, one wave per (b,h,s) ---------------- */
__global__ __launch_bounds__(256) void attn_feat(const unsigned short* __restrict__ qkv,
                                                 unsigned short* __restrict__ attn) {
  __shared__ float kk[5][64];
  __shared__ float vv[5][64];
  const int b = blockIdx.z, h = blockIdx.y;
  const int t = threadIdx.x;
  const size_t base = (size_t)b * SEQ;
  for (int i = t; i < 320; i += 256) {
    const int j = i >> 6, dd = i & 63;
    const size_t rb = (base + j) * 2304 + (size_t)h * 64 + dd;
    kk[j][dd] = bf2f(qkv[rb + 768]);
    vv[j][dd] = bf2f(qkv[rb + 1536]);
  }
  __syncthreads();
  const int wave = t >> 6, lane = t & 63;
  const int s = 5 + blockIdx.x * 4 + wave;
  const size_t row = (base + s) * 2304 + (size_t)h * 64;
  const float q = bf2f(qkv[row + lane]);
  const float kself = bf2f(qkv[row + 768 + lane]);
  const float vself = bf2f(qkv[row + 1536 + lane]);
  float sc[6];
#pragma unroll
  for (int j = 0; j < 5; j++) sc[j] = wave_sum(q * kk[j][lane]) * 0.125f;
  sc[5] = wave_sum(q * kself) * 0.125f;
  float mx = sc[0];
#pragma unroll
  for (int j = 1; j < 6; j++) mx = fmaxf(mx, sc[j]);
  float den = 0.f, e[6];
#pragma unroll
  for (int j = 0; j < 6; j++) { e[j] = expf(sc[j] - mx); den += e[j]; }
  const float inv = 1.0f / den;
  float o = 0.f;
#pragma unroll
  for (int j = 0; j < 5; j++) o += e[j] * vv[j][lane];
  o += e[5] * vself;
  attn[(base + s) * 768 + (size_t)h * 64 + lane] = f2bf(o * inv);
}

/* ---------------- attention, special rows 0..4: full softmax over 1029 keys ---------------- */
__global__ __launch_bounds__(256) void attn_special(const unsigned short* __restrict__ qkv,
                                                    unsigned short* __restrict__ attn) {
  __shared__ float qsh[64];
  __shared__ float sc[SEQ];
  __shared__ float red[256];
  __shared__ float outp[4][64];
  const int b = blockIdx.z, h = blockIdx.y, qi = blockIdx.x;
  const int t = threadIdx.x;
  const size_t base = (size_t)b * SEQ;
  if (t < 64) qsh[t] = bf2f(qkv[(base + qi) * 2304 + (size_t)h * 64 + t]);
  __syncthreads();
  float lmax = -1e30f;
  for (int key = t; key < SEQ; key += 256) {
    const unsigned short* kr = qkv + (base + key) * 2304 + 768 + (size_t)h * 64;
    const uint4* kr4 = (const uint4*)kr;
    float dot = 0.f;
#pragma unroll
    for (int c = 0; c < 8; c++) {
      const uint4 u = kr4[c];
      dot += qsh[c * 8 + 0] * bf_lo(u.x) + qsh[c * 8 + 1] * bf_hi(u.x)
           + qsh[c * 8 + 2] * bf_lo(u.y) + qsh[c * 8 + 3] * bf_hi(u.y)
           + qsh[c * 8 + 4] * bf_lo(u.z) + qsh[c * 8 + 5] * bf_hi(u.z)
           + qsh[c * 8 + 6] * bf_lo(u.w) + qsh[c * 8 + 7] * bf_hi(u.w);
    }
    const float v = dot * 0.125f;
    sc[key] = v;
    lmax = fmaxf(lmax, v);
  }
  red[t] = lmax;
  __syncthreads();
  for (int off = 128; off > 0; off >>= 1) {
    if (t < off) red[t] = fmaxf(red[t], red[t + off]);
    __syncthreads();
  }
  const float mx = red[0];
  __syncthreads();
  float lsum = 0.f;
  for (int key = t; key < SEQ; key += 256) {
    const float e = expf(sc[key] - mx);
    sc[key] = e;
    lsum += e;
  }
  red[t] = lsum;
  __syncthreads();
  for (int off = 128; off > 0; off >>= 1) {
    if (t < off) red[t] += red[t + off];
    __syncthreads();
  }
  const float inv = 1.0f / red[0];
  const int d = t & 63, grp = t >> 6;
  float o = 0.f;
  for (int key = grp; key < SEQ; key += 4) {
    o += sc[key] * bf2f(qkv[(base + key) * 2304 + 1536 + (size_t)h * 64 + d]);
  }
  outp[grp][d] = o;
  __syncthreads();
  if (t < 64) {
    const float sum = outp[0][d] + outp[1][d] + outp[2][d] + outp[3][d];
    attn[(base + qi) * 768 + (size_t)h * 64 + d] = f2bf(sum * inv);
  }
}

/* ---------------- LN2: wave per row over h1 (fp32) -> bf16 ---------------- */
__global__ __launch_bounds__(256) void ln2_kernel(const float* __restrict__ h1,
                                                  const float* __restrict__ g,
                                                  const float* __restrict__ bta,
                                                  unsigned short* __restrict__ out) {
  const int row = blockIdx.x * 4 + (threadIdx.x >> 6);
  const int lane = threadIdx.x & 63;
  const float* r = h1 + (size_t)row * 768;
  float vals[12], sm = 0.f, ss = 0.f;
#pragma unroll
  for (int i = 0; i < 12; i++) {
    const float v = r[lane + 64 * i];
    vals[i] = v; sm += v; ss += v * v;
  }
  sm = wave_sum(sm); ss = wave_sum(ss);
  const float mu = sm * (1.0f / 768.0f);
  const float var = ss * (1.0f / 768.0f) - mu * mu;
  const float rs = rsqrtf(var + 1e-5f);
  unsigned short* orow = out + (size_t)row * 768;
#pragma unroll
  for (int i = 0; i < 12; i++) {
    const int c = lane + 64 * i;
    orow[c] = f2bf((vals[i] - mu) * rs * g[c] + bta[c]);
  }
}

/* ---------------- final scatter: feature transpose (x<24) + ctx/reg copy (x==24) ---------------- */
__global__ __launch_bounds__(256) void scatter_all(const float* __restrict__ outb,
                                                   float* __restrict__ dout) {
  const int t = threadIdx.x;
  const int b = blockIdx.z;
  if (blockIdx.x == 24) {
    const int i = (b * 32 + blockIdx.y) * 256 + t;
    if (i >= 40 * 768) return;
    const int rowi = i / 768, c = i % 768;
    const int bb = rowi / 5, s = rowi % 5;
    const float v = outb[(size_t)(bb * SEQ + s) * 768 + c];
    if (s == 0) dout[6291456 + (size_t)bb * 768 + c] = v;
    else dout[6291456 + 6144 + ((size_t)bb * 4 + (s - 1)) * 768 + c] = v;
    return;
  }
  __shared__ float tl[32][33];
  const int hw0 = blockIdx.y * 32, c0 = blockIdx.x * 32;
  const int i = t >> 5, j = t & 31;
#pragma unroll
  for (int r = 0; r < 4; r++) {
    const int hwi = i + r * 8;
    tl[hwi][j] = outb[(size_t)(b * SEQ + 5 + hw0 + hwi) * 768 + c0 + j];
  }
  __syncthreads();
#pragma unroll
  for (int r = 0; r < 4; r++) {
    const int ci = i + r * 8;
    dout[(size_t)b * 768 * 1024 + (size_t)(c0 + ci) * 1024 + hw0 + j] = tl[j][ci];
  }
}

/* ---------------- host orchestration ---------------- */
extern "C" void kernel_launch(void* const* d_in, const int* in_sizes, int n_in,
                              void* d_out, int out_size, void* d_ws, size_t ws_size,
                              hipStream_t stream) {
  const float* x    = (const float*)d_in[0];
  const float* ctx  = (const float*)d_in[1];
  const float* regs = (const float*)d_in[2];
  const float* inw  = (const float*)d_in[3];
  const float* inb  = (const float*)d_in[4];
  const float* outw = (const float*)d_in[5];
  const float* outbi= (const float*)d_in[6];
  const float* ln1g = (const float*)d_in[7];
  const float* ln1b = (const float*)d_in[8];
  const float* ln2g = (const float*)d_in[9];
  const float* ln2b = (const float*)d_in[10];
  const float* w1   = (const float*)d_in[11];
  const float* b1   = (const float*)d_in[12];
  const float* w2   = (const float*)d_in[13];
  const float* b2   = (const float*)d_in[14];

  char* ws = (char*)d_ws;
  unsigned short* wqkv_b = (unsigned short*)(ws + 0);         /* 2304x768 bf16 */
  unsigned short* wout_b = (unsigned short*)(ws + 3538944);   /* 768x768 */
  unsigned short* w1_b   = (unsigned short*)(ws + 4718592);   /* 3072x768 */
  unsigned short* w2_b   = (unsigned short*)(ws + 9437184);   /* 768x3072 */
  unsigned short* xw_b   = (unsigned short*)(ws + 14155776);  /* M_PAD x 768 bf16 */
  unsigned short* ln2o_b = (unsigned short*)(ws + 26935296);  /* M_PAD x 768 bf16 */
  float*          h1_f   = (float*)(ws + 39714816);           /* M_PAD x 768 f32 */
  unsigned short* qkv_b  = (unsigned short*)(ws + 65273856);  /* M_PAD x 2304 bf16 */
  unsigned short* attn_b = (unsigned short*)(ws + 103612416); /* M_PAD x 768 bf16 */
  float*          out_f  = (float*)(ws + 14155776);           /* alias xw+ln2 (dead then) */
  unsigned short* ffm_b  = (unsigned short*)(ws + 65273856);  /* alias qkv+attn (dead then) */
  float* dout = (float*)d_out;

  /* fused prep: weights -> bf16, pad rows -> 0 */
  convert_all<<<(NQ_ALL + 255) / 256, 256, 0, stream>>>(
      (const float4*)inw, (const float4*)outw, (const float4*)w1, (const float4*)w2,
      (ushort4*)wqkv_b, (ushort4*)wout_b, (ushort4*)w1_b, (ushort4*)w2_b,
      (ushort4*)(xw_b + (size_t)M_TOT * 768), (ushort4*)(attn_b + (size_t)M_TOT * 768));

  /* LN1 (+ implicit transpose of x) */
  ln1_feat<<<dim3(64, 8), 256, 0, stream>>>(x, ln1g, ln1b, xw_b);
  ln1_special<<<10, 256, 0, stream>>>(ctx, regs, ln1g, ln1b, xw_b);

  /* QKV */
  gemm_bt<0, 768, 2304><<<dim3(2304 / BN, M_PAD / BM), 256, 0, stream>>>(
      xw_b, wqkv_b, inb, nullptr, nullptr, nullptr, qkv_b);

  /* attention */
  attn_feat<<<dim3(256, 12, 8), 256, 0, stream>>>(qkv_b, attn_b);
  attn_special<<<dim3(5, 12, 8), 256, 0, stream>>>(qkv_b, attn_b);

  /* out-proj + residual -> h1 (fp32) */
  gemm_bt<1, 768, 768><<<dim3(768 / BN, M_PAD / BM), 256, 0, stream>>>(
      attn_b, wout_b, outbi, xw_b, nullptr, h1_f, nullptr);

  /* LN2 */
  ln2_kernel<<<M_PAD / 4, 256, 0, stream>>>(h1_f, ln2g, ln2b, ln2o_b);

  /* FF1 + exact GELU */
  gemm_bt<2, 768, 3072><<<dim3(3072 / BN, M_PAD / BM), 256, 0, stream>>>(
      ln2o_b, w1_b, b1, nullptr, nullptr, nullptr, ffm_b);

  /* FF2 + h1 residual -> out (fp32) */
  gemm_bt<3, 3072, 768><<<dim3(768 / BN, M_PAD / BM), 256, 0, stream>>>(
      ffm_b, w2_b, b2, nullptr, h1_f, out_f, nullptr);

  /* scatter outputs */
  scatter_all<<<dim3(25, 32, 8), 256, 0, stream>>>(out_f, dout);
}

// Round 4
// 426.744 us; speedup vs baseline: 1.2442x; 1.1567x over previous
//
#include <hip/hip_runtime.h>
#include <math.h>
#include <stdint.h>

#define SEQ 1029
#define BATCH 8
#define M_TOT (BATCH * SEQ)   /* 8232 */
#define M_PAD 8320            /* 65 * 128 */
#define NCHUNK 17             /* 16 x 64 feature keys + 1 chunk of 5 special keys */

typedef float floatx4 __attribute__((ext_vector_type(4)));
typedef __bf16 bf16x8 __attribute__((ext_vector_type(8)));

__device__ __forceinline__ unsigned short f2bf(float f) {
  union { float f; unsigned u; } v; v.f = f;
  unsigned r = v.u + 0x7fffu + ((v.u >> 16) & 1u);
  return (unsigned short)(r >> 16);
}
__device__ __forceinline__ float bf2f(unsigned short h) {
  union { unsigned u; float f; } v; v.u = ((unsigned)h) << 16;
  return v.f;
}
__device__ __forceinline__ float bf_lo(unsigned u) { union { unsigned x; float f; } v; v.x = u << 16; return v.f; }
__device__ __forceinline__ float bf_hi(unsigned u) { union { unsigned x; float f; } v; v.x = u & 0xffff0000u; return v.f; }

__device__ __forceinline__ float wave_sum(float v) {
#pragma unroll
  for (int off = 32; off > 0; off >>= 1) v += __shfl_xor(v, off, 64);
  return v;
}
__device__ __forceinline__ float wave_max(float v) {
#pragma unroll
  for (int off = 32; off > 0; off >>= 1) v = fmaxf(v, __shfl_xor(v, off, 64));
  return v;
}

/* async global -> LDS, 16B per lane (DMA writes lds base + lane*16) */
__device__ __forceinline__ void gload16(const unsigned short* g, unsigned short* l) {
  __builtin_amdgcn_global_load_lds(
      (const __attribute__((address_space(1))) unsigned int*)g,
      (__attribute__((address_space(3))) unsigned int*)l, 16, 0, 0);
}

/* ---------------- fused prep: all weights fp32 -> bf16, plus zero-fill pad rows ---------------- */
#define NQ_QKV 442368
#define NQ_OUT 147456
#define NQ_W1  589824
#define NQ_W2  589824
#define NQ_PAD 8448   /* (M_PAD-M_TOT)*768/8 ushort4 quads */
__global__ void convert_all(const float4* __restrict__ inw, const float4* __restrict__ outw,
                            const float4* __restrict__ w1, const float4* __restrict__ w2,
                            ushort4* __restrict__ wqkv, ushort4* __restrict__ wout,
                            ushort4* __restrict__ w1b, ushort4* __restrict__ w2b,
                            ushort4* __restrict__ xw_pad, ushort4* __restrict__ attn_pad) {
  const int i = blockIdx.x * 256 + threadIdx.x;
  const float4* src; ushort4* dst; int off;
  if (i < NQ_QKV) { src = inw; dst = wqkv; off = i; }
  else if (i < NQ_QKV + NQ_OUT) { src = outw; dst = wout; off = i - NQ_QKV; }
  else if (i < NQ_QKV + NQ_OUT + NQ_W1) { src = w1; dst = w1b; off = i - NQ_QKV - NQ_OUT; }
  else if (i < NQ_QKV + NQ_OUT + NQ_W1 + NQ_W2) { src = w2; dst = w2b; off = i - NQ_QKV - NQ_OUT - NQ_W1; }
  else {
    const int j = i - (NQ_QKV + NQ_OUT + NQ_W1 + NQ_W2);
    const ushort4 z = {0, 0, 0, 0};
    if (j < NQ_PAD) { xw_pad[j] = z; attn_pad[j] = z; }
    return;
  }
  const float4 v = src[off];
  ushort4 o;
  o.x = f2bf(v.x); o.y = f2bf(v.y); o.z = f2bf(v.z); o.w = f2bf(v.w);
  dst[off] = o;
}
#define NQ_ALL (NQ_QKV + NQ_OUT + NQ_W1 + NQ_W2 + NQ_PAD)

/* ---------------- LN1 for feature tokens: transpose (B,C,HW)->(rows,C) + LN ---------------- */
__global__ __launch_bounds__(256) void ln1_feat(const float* __restrict__ x,
                                                const float* __restrict__ g,
                                                const float* __restrict__ bta,
                                                unsigned short* __restrict__ xw) {
  __shared__ float tile[768 * 17];  /* [c][hw], padded stride 17 */
  const int b = blockIdx.y;
  const int hw0 = blockIdx.x * 16;
  const int t = threadIdx.x;
  const float* xb = x + (size_t)b * 768 * 1024;
  const int cl = t >> 4, hl = t & 15;
  for (int it = 0; it < 48; it++) {
    const int c = it * 16 + cl;
    tile[c * 17 + hl] = xb[(size_t)c * 1024 + hw0 + hl];
  }
  __syncthreads();
  const int wave = t >> 6, lane = t & 63;
  for (int tk = wave; tk < 16; tk += 4) {
    float vals[12], s = 0.f, ss = 0.f;
#pragma unroll
    for (int i = 0; i < 12; i++) {
      const float v = tile[(lane + 64 * i) * 17 + tk];
      vals[i] = v; s += v; ss += v * v;
    }
    s = wave_sum(s); ss = wave_sum(ss);
    const float mu = s * (1.0f / 768.0f);
    const float var = ss * (1.0f / 768.0f) - mu * mu;
    const float rs = rsqrtf(var + 1e-5f);
    const int row = b * SEQ + 5 + hw0 + tk;
    unsigned short* orow = xw + (size_t)row * 768;
#pragma unroll
    for (int i = 0; i < 12; i++) {
      const int c = lane + 64 * i;
      orow[c] = f2bf((vals[i] - mu) * rs * g[c] + bta[c]);
    }
  }
}

/* ---------------- LN1 for ctx + register tokens (40 rows, one wave each) ---------------- */
__global__ __launch_bounds__(256) void ln1_special(const float* __restrict__ ctx,
                                                   const float* __restrict__ regs,
                                                   const float* __restrict__ g,
                                                   const float* __restrict__ bta,
                                                   unsigned short* __restrict__ xw) {
  const int gw = blockIdx.x * 4 + (threadIdx.x >> 6);
  const int lane = threadIdx.x & 63;
  if (gw >= 40) return;
  const int b = gw / 5, s = gw % 5;
  const float* src = (s == 0) ? (ctx + (size_t)b * 768)
                              : (regs + ((size_t)b * 4 + (s - 1)) * 768);
  float vals[12], sm = 0.f, ss = 0.f;
#pragma unroll
  for (int i = 0; i < 12; i++) {
    const float v = src[lane + 64 * i];
    vals[i] = v; sm += v; ss += v * v;
  }
  sm = wave_sum(sm); ss = wave_sum(ss);
  const float mu = sm * (1.0f / 768.0f);
  const float var = ss * (1.0f / 768.0f) - mu * mu;
  const float rs = rsqrtf(var + 1e-5f);
  unsigned short* orow = xw + (size_t)(b * SEQ + s) * 768;
#pragma unroll
  for (int i = 0; i < 12; i++) {
    const int c = lane + 64 * i;
    orow[c] = f2bf((vals[i] - mu) * rs * g[c] + bta[c]);
  }
}

/* ---------------- bf16 MFMA GEMM: C[M,N] = A[M,K] @ W[N,K]^T + bias, epilogues
   Double-buffered LDS (2x16KiB), ONE barrier per K-step; XOR chunk swizzle. ---------------- */
#define BM 128
#define BN 128
#define BK 32

template <int EPI, int K, int N>
__global__ __launch_bounds__(256, 4) void gemm_bt(const unsigned short* __restrict__ A,
                                                  const unsigned short* __restrict__ W,
                                                  const float* __restrict__ bias,
                                                  const unsigned short* __restrict__ residb,
                                                  const float* __restrict__ residf,
                                                  float* __restrict__ outf,
                                                  unsigned short* __restrict__ outb) {
  __shared__ alignas(16) unsigned short As[2][BM * BK];   /* 2 x 8 KiB */
  __shared__ alignas(16) unsigned short Ws[2][BN * BK];
  const int t = threadIdx.x;
  const int wave = t >> 6, lane = t & 63;
  const int quad = lane >> 4, l16 = lane & 15;
  const int wm = (wave & 1) * 64, wn = (wave >> 1) * 64;
  const int tileM = blockIdx.y * BM, tileN = blockIdx.x * BN;

  const int rl = lane >> 2;
  const int kc8 = ((lane & 3) ^ ((rl >> 1) & 3)) * 8;
  const unsigned short* Ag = A + (size_t)(tileM + wave * 16 + rl) * K;
  const unsigned short* Wg = W + (size_t)(tileN + wave * 16 + rl) * K;
  const int ldst = wave * 512 + lane * 8;

  const int koff = ((quad ^ ((l16 >> 1) & 3)) * 8);

  const floatx4 zero4 = {0.f, 0.f, 0.f, 0.f};
  floatx4 acc[4][4];
#pragma unroll
  for (int i = 0; i < 4; i++)
#pragma unroll
    for (int j = 0; j < 4; j++) acc[i][j] = zero4;

  auto dma = [&](int k0, int buf) {
    gload16(Ag + k0 + kc8, &As[buf][0] + ldst);
    gload16(Ag + (size_t)64 * K + k0 + kc8, &As[buf][0] + ldst + 2048);
    gload16(Wg + k0 + kc8, &Ws[buf][0] + ldst);
    gload16(Wg + (size_t)64 * K + k0 + kc8, &Ws[buf][0] + ldst + 2048);
  };
  auto compute = [&](int buf) {
    bf16x8 af[4], wf[4];
#pragma unroll
    for (int i = 0; i < 4; i++)
      af[i] = *(const bf16x8*)(&As[buf][0] + (wm + i * 16 + l16) * BK + koff);
#pragma unroll
    for (int j = 0; j < 4; j++)
      wf[j] = *(const bf16x8*)(&Ws[buf][0] + (wn + j * 16 + l16) * BK + koff);
#pragma unroll
    for (int i = 0; i < 4; i++)
#pragma unroll
      for (int j = 0; j < 4; j++)
        acc[i][j] = __builtin_amdgcn_mfma_f32_16x16x32_bf16(af[i], wf[j], acc[i][j], 0, 0, 0);
  };

  dma(0, 0);
#pragma unroll 1
  for (int k0 = 0; k0 < K; k0 += 2 * BK) {
    __syncthreads();
    if (k0 + BK < K) dma(k0 + BK, 1);
    compute(0);
    __syncthreads();
    if (k0 + 2 * BK < K) dma(k0 + 2 * BK, 0);
    compute(1);
  }

#pragma unroll
  for (int i = 0; i < 4; i++) {
    const int mbase = tileM + wm + i * 16 + quad * 4;
#pragma unroll
    for (int j = 0; j < 4; j++) {
      const int n = tileN + wn + j * 16 + l16;
      const float bv = bias[n];
#pragma unroll
      for (int r = 0; r < 4; r++) {
        const size_t idx = (size_t)(mbase + r) * N + n;
        float v = acc[i][j][r] + bv;
        if constexpr (EPI == 0) {
          outb[idx] = f2bf(v);
        } else if constexpr (EPI == 1) {
          outf[idx] = v + bf2f(residb[idx]);
        } else if constexpr (EPI == 2) {
          v = 0.5f * v * (1.0f + erff(v * 0.70710678118654752f));
          outb[idx] = f2bf(v);
        } else {
          outf[idx] = v + residf[idx];
        }
      }
    }
  }
}

/* ---------------- attention, feature rows: 6-key softmax, one wave per (b,h,s) ---------------- */
__global__ __launch_bounds__(256) void attn_feat(const unsigned short* __restrict__ qkv,
                                                 unsigned short* __restrict__ attn) {
  __shared__ float kk[5][64];
  __shared__ float vv[5][64];
  const int b = blockIdx.z, h = blockIdx.y;
  const int t = threadIdx.x;
  const size_t base = (size_t)b * SEQ;
  for (int i = t; i < 320; i += 256) {
    const int j = i >> 6, dd = i & 63;
    const size_t rb = (base + j) * 2304 + (size_t)h * 64 + dd;
    kk[j][dd] = bf2f(qkv[rb + 768]);
    vv[j][dd] = bf2f(qkv[rb + 1536]);
  }
  __syncthreads();
  const int wave = t >> 6, lane = t & 63;
  const int s = 5 + blockIdx.x * 4 + wave;
  const size_t row = (base + s) * 2304 + (size_t)h * 64;
  const float q = bf2f(qkv[row + lane]);
  const float kself = bf2f(qkv[row + 768 + lane]);
  const float vself = bf2f(qkv[row + 1536 + lane]);
  float sc[6];
#pragma unroll
  for (int j = 0; j < 5; j++) sc[j] = wave_sum(q * kk[j][lane]) * 0.125f;
  sc[5] = wave_sum(q * kself) * 0.125f;
  float mx = sc[0];
#pragma unroll
  for (int j = 1; j < 6; j++) mx = fmaxf(mx, sc[j]);
  float den = 0.f, e[6];
#pragma unroll
  for (int j = 0; j < 6; j++) { e[j] = expf(sc[j] - mx); den += e[j]; }
  const float inv = 1.0f / den;
  float o = 0.f;
#pragma unroll
  for (int j = 0; j < 5; j++) o += e[j] * vv[j][lane];
  o += e[5] * vself;
  attn[(base + s) * 768 + (size_t)h * 64 + lane] = f2bf(o * inv);
}

/* ---------------- special rows 0..4, split-K phase 1: per-64-key-chunk partials
   Block = (chunk, h, b). 5 queries processed together; K,V each read exactly once.
   Writes (m, l, o[64]) per (q, chunk) to workspace. ---------------- */
__global__ __launch_bounds__(256) void attn_part(const unsigned short* __restrict__ qkv,
                                                 float* __restrict__ part) {
  __shared__ float qs[5][64];
  __shared__ float sc[5][64];   /* scores, then exp(s-m) */
  __shared__ float mArr[5], lArr[5];
  __shared__ float og[4][320];
  const int c = blockIdx.x, h = blockIdx.y, b = blockIdx.z;
  const int t = threadIdx.x;
  const size_t base = (size_t)b * SEQ;
  const int kbase = (c < 16) ? (5 + 64 * c) : 0;
  const int nvalid = (c < 16) ? 64 : 5;

  for (int i = t; i < 320; i += 256)
    qs[i >> 6][i & 63] = bf2f(qkv[(base + (i >> 6)) * 2304 + (size_t)h * 64 + (i & 63)]);
  __syncthreads();

  /* stage 1: scores. quad per key: lane dc covers dims {8dc..8dc+8} U {8dc+32..+8} */
  const int keyloc = t >> 2, dc = t & 3;
  const int key = kbase + keyloc;
  const unsigned short* krow = qkv + (base + key) * 2304 + 768 + (size_t)h * 64;
  const uint4 k0 = *(const uint4*)(krow + dc * 8);
  const uint4 k1 = *(const uint4*)(krow + dc * 8 + 32);
  float kf[16];
  {
    const unsigned ku[8] = {k0.x, k0.y, k0.z, k0.w, k1.x, k1.y, k1.z, k1.w};
#pragma unroll
    for (int j = 0; j < 8; j++) { kf[2 * j] = bf_lo(ku[j]); kf[2 * j + 1] = bf_hi(ku[j]); }
  }
#pragma unroll
  for (int q = 0; q < 5; q++) {
    const float* qp = qs[q];
    float d0 = 0.f;
#pragma unroll
    for (int j = 0; j < 8; j++) d0 += qp[dc * 8 + j] * kf[j];
#pragma unroll
    for (int j = 0; j < 8; j++) d0 += qp[dc * 8 + 32 + j] * kf[8 + j];
    d0 += __shfl_xor(d0, 1, 64);
    d0 += __shfl_xor(d0, 2, 64);
    if (dc == 0) sc[q][keyloc] = (keyloc < nvalid) ? d0 * 0.125f : -1e30f;
  }
  __syncthreads();

  /* per-q chunk max/sum, exp in place; wave w handles q = w (+4) */
  const int wave = t >> 6, lane = t & 63;
  for (int q = wave; q < 5; q += 4) {
    const float v = sc[q][lane];
    const float m = wave_max(v);
    const float e = expf(v - m);
    sc[q][lane] = e;
    const float l = wave_sum(e);
    if (lane == 0) { mArr[q] = m; lArr[q] = l; }
  }
  __syncthreads();

  /* stage 2: partial O. thread (d = t&63, g = t>>6) loops 16 keys of its group */
  const int d = t & 63, g = t >> 6;
  float o[5] = {0.f, 0.f, 0.f, 0.f, 0.f};
  for (int i = 0; i < 16; i++) {
    const int kl = g * 16 + i;
    const float v = bf2f(qkv[(base + kbase + kl) * 2304 + 1536 + (size_t)h * 64 + d]);
#pragma unroll
    for (int q = 0; q < 5; q++) o[q] += sc[q][kl] * v;
  }
#pragma unroll
  for (int q = 0; q < 5; q++) og[g][q * 64 + d] = o[q];
  __syncthreads();

  float* pw = part + (size_t)((b * 12 + h) * NCHUNK + c) * 5 * 66;
  for (int i = t; i < 320; i += 256) {
    const int q = i >> 6, dd = i & 63;
    pw[q * 66 + 2 + dd] = og[0][i] + og[1][i] + og[2][i] + og[3][i];
    if (dd == 0) { pw[q * 66] = mArr[q]; pw[q * 66 + 1] = lArr[q]; }
  }
}

/* ---------------- split-K phase 2: online-merge 17 chunk partials ---------------- */
__global__ __launch_bounds__(64) void attn_comb(const float* __restrict__ part,
                                                unsigned short* __restrict__ attn) {
  const int qi = blockIdx.x, h = blockIdx.y, b = blockIdx.z;
  const int d = threadIdx.x;
  float M = -3e38f, L = 0.f, o = 0.f;
  for (int c = 0; c < NCHUNK; c++) {
    const float* p = part + ((size_t)((b * 12 + h) * NCHUNK + c) * 5 + qi) * 66;
    const float mc = p[0], lc = p[1], oc = p[2 + d];
    if (mc > M) {
      const float s = expf(M - mc);
      L = L * s + lc; o = o * s + oc; M = mc;
    } else {
      const float w = expf(mc - M);
      L += lc * w; o += oc * w;
    }
  }
  attn[((size_t)b * SEQ + qi) * 768 + (size_t)h * 64 + d] = f2bf(o / L);
}

/* ---------------- LN2: wave per row over h1 (fp32) -> bf16 ---------------- */
__global__ __launch_bounds__(256) void ln2_kernel(const float* __restrict__ h1,
                                                  const float* __restrict__ g,
                                                  const float* __restrict__ bta,
                                                  unsigned short* __restrict__ out) {
  const int row = blockIdx.x * 4 + (threadIdx.x >> 6);
  const int lane = threadIdx.x & 63;
  const float* r = h1 + (size_t)row * 768;
  float vals[12], sm = 0.f, ss = 0.f;
#pragma unroll
  for (int i = 0; i < 12; i++) {
    const float v = r[lane + 64 * i];
    vals[i] = v; sm += v; ss += v * v;
  }
  sm = wave_sum(sm); ss = wave_sum(ss);
  const float mu = sm * (1.0f / 768.0f);
  const float var = ss * (1.0f / 768.0f) - mu * mu;
  const float rs = rsqrtf(var + 1e-5f);
  unsigned short* orow = out + (size_t)row * 768;
#pragma unroll
  for (int i = 0; i < 12; i++) {
    const int c = lane + 64 * i;
    orow[c] = f2bf((vals[i] - mu) * rs * g[c] + bta[c]);
  }
}

/* ---------------- final scatter: feature transpose (x<24) + ctx/reg copy (x==24) ---------------- */
__global__ __launch_bounds__(256) void scatter_all(const float* __restrict__ outb,
                                                   float* __restrict__ dout) {
  const int t = threadIdx.x;
  const int b = blockIdx.z;
  if (blockIdx.x == 24) {
    const int i = (b * 32 + blockIdx.y) * 256 + t;
    if (i >= 40 * 768) return;
    const int rowi = i / 768, c = i % 768;
    const int bb = rowi / 5, s = rowi % 5;
    const float v = outb[(size_t)(bb * SEQ + s) * 768 + c];
    if (s == 0) dout[6291456 + (size_t)bb * 768 + c] = v;
    else dout[6291456 + 6144 + ((size_t)bb * 4 + (s - 1)) * 768 + c] = v;
    return;
  }
  __shared__ float tl[32][33];
  const int hw0 = blockIdx.y * 32, c0 = blockIdx.x * 32;
  const int i = t >> 5, j = t & 31;
#pragma unroll
  for (int r = 0; r < 4; r++) {
    const int hwi = i + r * 8;
    tl[hwi][j] = outb[(size_t)(b * SEQ + 5 + hw0 + hwi) * 768 + c0 + j];
  }
  __syncthreads();
#pragma unroll
  for (int r = 0; r < 4; r++) {
    const int ci = i + r * 8;
    dout[(size_t)b * 768 * 1024 + (size_t)(c0 + ci) * 1024 + hw0 + j] = tl[j][ci];
  }
}

/* ---------------- host orchestration ---------------- */
extern "C" void kernel_launch(void* const* d_in, const int* in_sizes, int n_in,
                              void* d_out, int out_size, void* d_ws, size_t ws_size,
                              hipStream_t stream) {
  const float* x    = (const float*)d_in[0];
  const float* ctx  = (const float*)d_in[1];
  const float* regs = (const float*)d_in[2];
  const float* inw  = (const float*)d_in[3];
  const float* inb  = (const float*)d_in[4];
  const float* outw = (const float*)d_in[5];
  const float* outbi= (const float*)d_in[6];
  const float* ln1g = (const float*)d_in[7];
  const float* ln1b = (const float*)d_in[8];
  const float* ln2g = (const float*)d_in[9];
  const float* ln2b = (const float*)d_in[10];
  const float* w1   = (const float*)d_in[11];
  const float* b1   = (const float*)d_in[12];
  const float* w2   = (const float*)d_in[13];
  const float* b2   = (const float*)d_in[14];

  char* ws = (char*)d_ws;
  unsigned short* wqkv_b = (unsigned short*)(ws + 0);         /* 2304x768 bf16 */
  unsigned short* wout_b = (unsigned short*)(ws + 3538944);   /* 768x768 */
  unsigned short* w1_b   = (unsigned short*)(ws + 4718592);   /* 3072x768 */
  unsigned short* w2_b   = (unsigned short*)(ws + 9437184);   /* 768x3072 */
  unsigned short* xw_b   = (unsigned short*)(ws + 14155776);  /* M_PAD x 768 bf16 */
  unsigned short* ln2o_b = (unsigned short*)(ws + 26935296);  /* M_PAD x 768 bf16 */
  float*          h1_f   = (float*)(ws + 39714816);           /* M_PAD x 768 f32 */
  unsigned short* qkv_b  = (unsigned short*)(ws + 65273856);  /* M_PAD x 2304 bf16 */
  unsigned short* attn_b = (unsigned short*)(ws + 103612416); /* M_PAD x 768 bf16 */
  float*          out_f  = (float*)(ws + 14155776);           /* alias xw+ln2 (dead then) */
  unsigned short* ffm_b  = (unsigned short*)(ws + 65273856);  /* alias qkv+attn (dead then) */
  float*          part_f = (float*)(ws + 39714816);           /* alias h1_f (dead during attention) */
  float* dout = (float*)d_out;

  /* fused prep: weights -> bf16, pad rows -> 0 */
  convert_all<<<(NQ_ALL + 255) / 256, 256, 0, stream>>>(
      (const float4*)inw, (const float4*)outw, (const float4*)w1, (const float4*)w2,
      (ushort4*)wqkv_b, (ushort4*)wout_b, (ushort4*)w1_b, (ushort4*)w2_b,
      (ushort4*)(xw_b + (size_t)M_TOT * 768), (ushort4*)(attn_b + (size_t)M_TOT * 768));

  /* LN1 (+ implicit transpose of x) */
  ln1_feat<<<dim3(64, 8), 256, 0, stream>>>(x, ln1g, ln1b, xw_b);
  ln1_special<<<10, 256, 0, stream>>>(ctx, regs, ln1g, ln1b, xw_b);

  /* QKV */
  gemm_bt<0, 768, 2304><<<dim3(2304 / BN, M_PAD / BM), 256, 0, stream>>>(
      xw_b, wqkv_b, inb, nullptr, nullptr, nullptr, qkv_b);

  /* attention */
  attn_feat<<<dim3(256, 12, 8), 256, 0, stream>>>(qkv_b, attn_b);
  attn_part<<<dim3(NCHUNK, 12, 8), 256, 0, stream>>>(qkv_b, part_f);
  attn_comb<<<dim3(5, 12, 8), 64, 0, stream>>>(part_f, attn_b);

  /* out-proj + residual -> h1 (fp32) */
  gemm_bt<1, 768, 768><<<dim3(768 / BN, M_PAD / BM), 256, 0, stream>>>(
      attn_b, wout_b, outbi, xw_b, nullptr, h1_f, nullptr);

  /* LN2 */
  ln2_kernel<<<M_PAD / 4, 256, 0, stream>>>(h1_f, ln2g, ln2b, ln2o_b);

  /* FF1 + exact GELU */
  gemm_bt<2, 768, 3072><<<dim3(3072 / BN, M_PAD / BM), 256, 0, stream>>>(
      ln2o_b, w1_b, b1, nullptr, nullptr, nullptr, ffm_b);

  /* FF2 + h1 residual -> out (fp32) */
  gemm_bt<3, 3072, 768><<<dim3(768 / BN, M_PAD / BM), 256, 0, stream>>>(
      ffm_b, w2_b, b2, nullptr, h1_f, out_f, nullptr);

  /* scatter outputs */
  scatter_all<<<dim3(25, 32, 8), 256, 0, stream>>>(out_f, dout);
}